// Round 11
// baseline (34.920 us; speedup 1.0000x reference)
//
#include <hip/hip_runtime.h>

// out[j] = sum_i alpha[i] * T[lab_obs[i], lab_x[j]] * matern52(xobs[i], x[j]; ls)
// N = M = 8192, D = 8, ND = 4; domain edges are multiples of 2048.
//
// u_ij = 5*log2e^2 * d_ij^2 computed ENTIRELY by one mfma_f32_16x16x32_bf16
// (split-bf16 K-packing, na/nb seeds in K-slots 24..27, C=0) -- r7-proven.
// Tail: t = sqrt(u)  [the ONLY transcendental];  2^-t computed on the
// full-rate VALU: n = rint(t), r = n-t in [-1/2,1/2], 2^r by deg-3 Horner,
// 2^-n by integer exponent build (127-n)<<23.  Rationale: r7/r9/r10 A/Bs
// localize the wall to transcendental-pipe occupancy; halving trans ops
// converts trans-pipe time into cheap VALU cycles.
// Transfer factor w is block-uniform, applied at the partial store; partials
// in d_ws, summed by reduce_cols.

typedef __attribute__((ext_vector_type(8))) short short8v;
typedef __attribute__((ext_vector_type(4))) float f32x4;
typedef __attribute__((ext_vector_type(4))) unsigned int u32x4;

#define BLOCK 256
#define DPT 8
#define COLS_PER_BLOCK 128
#define ROWS_PER_BLOCK 256
#define NIT (ROWS_PER_BLOCK / 16)
#define RSTRIDE 48               // bytes per packed LDS row: hi16 | lo16 | seed16

__device__ __forceinline__ void split_pair(float a0, float a1,
                                           unsigned& hi, unsigned& lo) {
    unsigned u0 = __builtin_bit_cast(unsigned, a0);
    unsigned u1 = __builtin_bit_cast(unsigned, a1);
    unsigned h0 = u0 & 0xffff0000u, h1 = u1 & 0xffff0000u;
    float r0 = a0 - __builtin_bit_cast(float, h0);
    float r1 = a1 - __builtin_bit_cast(float, h1);
    unsigned l0 = __builtin_bit_cast(unsigned, r0);
    unsigned l1 = __builtin_bit_cast(unsigned, r1);
    hi = (h0 >> 16) | h1;
    lo = (l0 >> 16) | (l1 & 0xffff0000u);
}

// split one nonnegative float into packed (hi | lo<<16) bf16 words
__device__ __forceinline__ unsigned split_scalar(float a) {
    unsigned u0 = __builtin_bit_cast(unsigned, a);
    unsigned h0 = u0 & 0xffff0000u;
    float r0 = a - __builtin_bit_cast(float, h0);
    unsigned l0 = __builtin_bit_cast(unsigned, r0);
    return (h0 >> 16) | (l0 & 0xffff0000u);
}

__global__ __launch_bounds__(256, 4) void matern_main(
    const float* __restrict__ x, const float* __restrict__ xobs,
    const float* __restrict__ alpha, const float* __restrict__ tfl,
    const float* __restrict__ ls, const int* __restrict__ dro,
    const int* __restrict__ drx,
    float* __restrict__ part, int M, int N, int ND)
{
    __shared__ __align__(16) char lds[ROWS_PER_BLOCK * RSTRIDE + ROWS_PER_BLOCK * 4];

    const int tid  = threadIdx.x;
    const int wave = tid >> 6;
    const int lane = tid & 63;
    const int g    = lane >> 4;
    const int r15  = lane & 15;

    const int colBase = blockIdx.x * COLS_PER_BLOCK;
    const int rowBase = blockIdx.y * ROWS_PER_BLOCK;

    // 5 * log2(e)^2 folded into the length-scale
    const float rls   = 1.0f / ls[0];
    const float rls2p = 10.406844905028039f * rls * rls;
    const float m2p   = -2.0f * rls2p;

    // ---- pack: thread t -> row rowBase+t into LDS (48B row + al) ----
    {
        const int i = rowBase + tid;
        unsigned hi[4] = {0,0,0,0}, lo[4] = {0,0,0,0};
        float na = 0.0f, al = 0.0f;
        if (i < N) {
            float4 p0 = *(const float4*)(xobs + (size_t)i * DPT);
            float4 p1 = *(const float4*)(xobs + (size_t)i * DPT + 4);
            float vv[8] = {p0.x, p0.y, p0.z, p0.w, p1.x, p1.y, p1.z, p1.w};
            #pragma unroll
            for (int k = 0; k < 4; ++k) {
                float a0 = vv[2*k], a1 = vv[2*k+1];
                na += a0*a0 + a1*a1;
                split_pair(a0*m2p, a1*m2p, hi[k], lo[k]);
            }
            na *= rls2p;
            al  = alpha[i];
        }
        char* rb = lds + tid * RSTRIDE;
        *(u32x4*)(rb)      = u32x4{hi[0], hi[1], hi[2], hi[3]};
        *(u32x4*)(rb + 16) = u32x4{lo[0], lo[1], lo[2], lo[3]};
        *(u32x4*)(rb + 32) = u32x4{split_scalar(na), 0x3F803F80u, 0u, 0u};
        *(float*)(lds + ROWS_PER_BLOCK * RSTRIDE + tid * 4) = al;
    }

    // ---- block-uniform transfer factor ----
    int labj = ND, labi = ND;
    for (int d = 0; d < ND; ++d) {
        if (colBase >= drx[2*d] && colBase < drx[2*d+1]) labj = d;
        if (rowBase >= dro[2*d] && rowBase < dro[2*d+1]) labi = d;
    }
    float w = 1.0f;
    if (labi != labj && labi < ND && labj < ND) {
        int a_ = min(labi, labj), b_ = max(labi, labj);
        int n  = a_ * (2*ND - a_ - 1) / 2 + (b_ - a_ - 1);
        w = 1.0f / (1.0f + __expf(-tfl[n]));
    }

    // ---- column fragments: 2 groups of 16 cols per wave, in registers ----
    const int j0 = colBase + wave * 32 + r15;
    const int j1 = j0 + 16;
    short8v bfrag[2];
    #pragma unroll
    for (int c = 0; c < 2; ++c) {
        const int j = (c == 0) ? j0 : j1;
        float vv[8];
        if (j < M) {
            float4 p0 = *(const float4*)(x + (size_t)j * DPT);
            float4 p1 = *(const float4*)(x + (size_t)j * DPT + 4);
            vv[0]=p0.x; vv[1]=p0.y; vv[2]=p0.z; vv[3]=p0.w;
            vv[4]=p1.x; vv[5]=p1.y; vv[6]=p1.z; vv[7]=p1.w;
        } else {
            #pragma unroll
            for (int k = 0; k < 8; ++k) vv[k] = 0.0f;
        }
        float s2 = 0.0f;
        unsigned bh[4], bl[4];
        #pragma unroll
        for (int k = 0; k < 4; ++k) {
            s2 += vv[2*k]*vv[2*k] + vv[2*k+1]*vv[2*k+1];
            split_pair(vv[2*k], vv[2*k+1], bh[k], bl[k]);
        }
        const unsigned nbw = split_scalar(s2 * rls2p);
        u32x4 bw;
        #pragma unroll
        for (int k = 0; k < 4; ++k) {
            unsigned seed = (k == 0) ? 0x3F803F80u : ((k == 1) ? nbw : 0u);
            bw[k] = (g == 3) ? seed : ((g == 2) ? bl[k] : bh[k]);
        }
        bfrag[c] = __builtin_bit_cast(short8v, bw);
    }

    __syncthreads();

    // ---- compute: NIT iterations of 16 rows x 32 cols ----
    const float LN2   = 0.6931471805599453f;
    const float LN2S3 = 0.16015660576973906f;   // ln2^2 / 3
    const float E1    = 0.6931471805599453f;    // ln2      (2^r Horner)
    const float E2    = 0.2402265069591007f;    // ln2^2/2
    const float E3    = 0.0555041086648216f;    // ln2^3/6

    // A-fragment part select: g0/g2 -> hi, g1 -> lo, g3 -> seed
    const int poff  = (g == 1) ? 16 : ((g == 3) ? 32 : 0);
    const char* pa  = lds + r15 * RSTRIDE + poff;
    const char* pal = lds + ROWS_PER_BLOCK * RSTRIDE + g * 16;

    f32x4 zq = {0.0f, 0.0f, 0.0f, 0.0f};
    float acc0 = 0.0f, acc1 = 0.0f;

    #pragma unroll 4
    for (int it = 0; it < NIT; ++it) {
        short8v afrag = *(const short8v*)(pa + it * (16 * RSTRIDE));
        f32x4   cal   = *(const f32x4*)(pal + it * 64);

        f32x4 d0 = __builtin_amdgcn_mfma_f32_16x16x32_bf16(afrag, bfrag[0], zq, 0, 0, 0);
        f32x4 d1 = __builtin_amdgcn_mfma_f32_16x16x32_bf16(afrag, bfrag[1], zq, 0, 0, 0);

        #pragma unroll
        for (int q = 0; q < 4; ++q) {
            // --- pair 0 ---
            float u0 = fmaxf(d0[q], 1e-20f);
            float t0 = __builtin_amdgcn_sqrtf(u0);          // only trans op
            float n0 = __builtin_rintf(t0);
            float r0 = n0 - t0;                             // [-0.5, 0.5]
            float pr0 = fmaf(r0, fmaf(r0, fmaf(r0, E3, E2), E1), 1.0f);  // 2^r
            int   ni0 = (int)n0;
            float eb0 = __builtin_bit_cast(float, 0x3F800000 - (ni0 << 23)); // 2^-n
            float pm0 = fmaf(LN2, t0, fmaf(LN2S3, u0, 1.0f));
            acc0 = fmaf(pm0 * pr0 * eb0, cal[q], acc0);
            // --- pair 1 ---
            float u1 = fmaxf(d1[q], 1e-20f);
            float t1 = __builtin_amdgcn_sqrtf(u1);
            float n1 = __builtin_rintf(t1);
            float r1 = n1 - t1;
            float pr1 = fmaf(r1, fmaf(r1, fmaf(r1, E3, E2), E1), 1.0f);
            int   ni1 = (int)n1;
            float eb1 = __builtin_bit_cast(float, 0x3F800000 - (ni1 << 23));
            float pm1 = fmaf(LN2, t1, fmaf(LN2S3, u1, 1.0f));
            acc1 = fmaf(pm1 * pr1 * eb1, cal[q], acc1);
        }
    }

    // reduce over the 4 row-groups; lanes 0-15 of each wave hold column sums
    acc0 += __shfl_xor(acc0, 16);
    acc0 += __shfl_xor(acc0, 32);
    acc1 += __shfl_xor(acc1, 16);
    acc1 += __shfl_xor(acc1, 32);
    if (g == 0) {
        float* dst = part + (size_t)blockIdx.y * M;
        if (j0 < M) dst[j0] = w * acc0;
        if (j1 < M) dst[j1] = w * acc1;
    }
}

__global__ __launch_bounds__(128) void reduce_cols(
    const float* __restrict__ part, float* __restrict__ out,
    int M, int nparts)
{
    const int j = blockIdx.x * 128 + threadIdx.x;
    if (j >= M) return;
    float a = 0.0f;
    #pragma unroll 8
    for (int k = 0; k < nparts; ++k)
        a += part[(size_t)k * M + j];
    out[j] = a;
}

extern "C" void kernel_launch(void* const* d_in, const int* in_sizes, int n_in,
                              void* d_out, int out_size, void* d_ws, size_t ws_size,
                              hipStream_t stream) {
    const float* x     = (const float*)d_in[0];
    const float* xobs  = (const float*)d_in[1];
    const float* alpha = (const float*)d_in[2];
    const float* tfl   = (const float*)d_in[3];
    const float* ls    = (const float*)d_in[4];
    const int*   dro   = (const int*)d_in[5];
    const int*   drx   = (const int*)d_in[6];
    float* out = (float*)d_out;

    const int M  = in_sizes[0] / DPT;
    const int N  = in_sizes[1] / DPT;
    const int ND = in_sizes[5] / 2;
    const int nparts = (N + ROWS_PER_BLOCK - 1) / ROWS_PER_BLOCK;

    float* part = (float*)d_ws;   // nparts * M * 4 B

    dim3 grid((M + COLS_PER_BLOCK - 1) / COLS_PER_BLOCK, nparts);
    matern_main<<<grid, dim3(BLOCK), 0, stream>>>(
        x, xobs, alpha, tfl, ls, dro, drx, part, M, N, ND);

    reduce_cols<<<dim3((M + 127) / 128), dim3(128), 0, stream>>>(
        part, out, M, nparts);
}

// Round 12
// 27.043 us; speedup vs baseline: 1.2913x; 1.2913x over previous
//
#include <hip/hip_runtime.h>

// out[j] = sum_i alpha[i] * T[lab_obs[i], lab_x[j]] * matern52(xobs[i], x[j]; ls)
// N = M = 8192, D = 8, ND = 4; domain edges are multiples of 2048.
//
// u_ij = 5*log2e^2 * d_ij^2 computed ENTIRELY by one mfma_f32_16x16x32_bf16
// (split-bf16 K-packing, na/nb seeds in K-slots 24..27, C=0) -- r7-proven.
// Tail: t=sqrt(u), k=(1+ln2*t+ln2^2/3*u)*2^-t with the two independent
// column-chains (j0,j1) evaluated as float2 so the backend emits packed
// v_pk_fma_f32 / v_pk_mul_f32 / v_pk_max_f32 (VOP3P): VALU issue halves
// (5 -> 2.5 ops/pair), trans count unchanged (cheapest measured: r9 LUT and
// r11 poly were both slower).
// Transfer factor w is block-uniform, applied at the partial store; partials
// in d_ws, summed by reduce_cols.

typedef __attribute__((ext_vector_type(8))) short short8v;
typedef __attribute__((ext_vector_type(4))) float f32x4;
typedef __attribute__((ext_vector_type(2))) float f32x2;
typedef __attribute__((ext_vector_type(4))) unsigned int u32x4;

#define BLOCK 256
#define DPT 8
#define COLS_PER_BLOCK 128
#define ROWS_PER_BLOCK 256
#define NIT (ROWS_PER_BLOCK / 16)
#define RSTRIDE 48               // bytes per packed LDS row: hi16 | lo16 | seed16

__device__ __forceinline__ void split_pair(float a0, float a1,
                                           unsigned& hi, unsigned& lo) {
    unsigned u0 = __builtin_bit_cast(unsigned, a0);
    unsigned u1 = __builtin_bit_cast(unsigned, a1);
    unsigned h0 = u0 & 0xffff0000u, h1 = u1 & 0xffff0000u;
    float r0 = a0 - __builtin_bit_cast(float, h0);
    float r1 = a1 - __builtin_bit_cast(float, h1);
    unsigned l0 = __builtin_bit_cast(unsigned, r0);
    unsigned l1 = __builtin_bit_cast(unsigned, r1);
    hi = (h0 >> 16) | h1;
    lo = (l0 >> 16) | (l1 & 0xffff0000u);
}

// split one nonnegative float into packed (hi | lo<<16) bf16 words
__device__ __forceinline__ unsigned split_scalar(float a) {
    unsigned u0 = __builtin_bit_cast(unsigned, a);
    unsigned h0 = u0 & 0xffff0000u;
    float r0 = a - __builtin_bit_cast(float, h0);
    unsigned l0 = __builtin_bit_cast(unsigned, r0);
    return (h0 >> 16) | (l0 & 0xffff0000u);
}

__global__ __launch_bounds__(256, 4) void matern_main(
    const float* __restrict__ x, const float* __restrict__ xobs,
    const float* __restrict__ alpha, const float* __restrict__ tfl,
    const float* __restrict__ ls, const int* __restrict__ dro,
    const int* __restrict__ drx,
    float* __restrict__ part, int M, int N, int ND)
{
    __shared__ __align__(16) char lds[ROWS_PER_BLOCK * RSTRIDE + ROWS_PER_BLOCK * 4];

    const int tid  = threadIdx.x;
    const int wave = tid >> 6;
    const int lane = tid & 63;
    const int g    = lane >> 4;
    const int r15  = lane & 15;

    const int colBase = blockIdx.x * COLS_PER_BLOCK;
    const int rowBase = blockIdx.y * ROWS_PER_BLOCK;

    // 5 * log2(e)^2 folded into the length-scale
    const float rls   = 1.0f / ls[0];
    const float rls2p = 10.406844905028039f * rls * rls;
    const float m2p   = -2.0f * rls2p;

    // ---- pack: thread t -> row rowBase+t into LDS (48B row + al) ----
    {
        const int i = rowBase + tid;
        unsigned hi[4] = {0,0,0,0}, lo[4] = {0,0,0,0};
        float na = 0.0f, al = 0.0f;
        if (i < N) {
            float4 p0 = *(const float4*)(xobs + (size_t)i * DPT);
            float4 p1 = *(const float4*)(xobs + (size_t)i * DPT + 4);
            float vv[8] = {p0.x, p0.y, p0.z, p0.w, p1.x, p1.y, p1.z, p1.w};
            #pragma unroll
            for (int k = 0; k < 4; ++k) {
                float a0 = vv[2*k], a1 = vv[2*k+1];
                na += a0*a0 + a1*a1;
                split_pair(a0*m2p, a1*m2p, hi[k], lo[k]);
            }
            na *= rls2p;
            al  = alpha[i];
        }
        char* rb = lds + tid * RSTRIDE;
        *(u32x4*)(rb)      = u32x4{hi[0], hi[1], hi[2], hi[3]};
        *(u32x4*)(rb + 16) = u32x4{lo[0], lo[1], lo[2], lo[3]};
        *(u32x4*)(rb + 32) = u32x4{split_scalar(na), 0x3F803F80u, 0u, 0u};
        *(float*)(lds + ROWS_PER_BLOCK * RSTRIDE + tid * 4) = al;
    }

    // ---- block-uniform transfer factor ----
    int labj = ND, labi = ND;
    for (int d = 0; d < ND; ++d) {
        if (colBase >= drx[2*d] && colBase < drx[2*d+1]) labj = d;
        if (rowBase >= dro[2*d] && rowBase < dro[2*d+1]) labi = d;
    }
    float w = 1.0f;
    if (labi != labj && labi < ND && labj < ND) {
        int a_ = min(labi, labj), b_ = max(labi, labj);
        int n  = a_ * (2*ND - a_ - 1) / 2 + (b_ - a_ - 1);
        w = 1.0f / (1.0f + __expf(-tfl[n]));
    }

    // ---- column fragments: 2 groups of 16 cols per wave, in registers ----
    const int j0 = colBase + wave * 32 + r15;
    const int j1 = j0 + 16;
    short8v bfrag[2];
    #pragma unroll
    for (int c = 0; c < 2; ++c) {
        const int j = (c == 0) ? j0 : j1;
        float vv[8];
        if (j < M) {
            float4 p0 = *(const float4*)(x + (size_t)j * DPT);
            float4 p1 = *(const float4*)(x + (size_t)j * DPT + 4);
            vv[0]=p0.x; vv[1]=p0.y; vv[2]=p0.z; vv[3]=p0.w;
            vv[4]=p1.x; vv[5]=p1.y; vv[6]=p1.z; vv[7]=p1.w;
        } else {
            #pragma unroll
            for (int k = 0; k < 8; ++k) vv[k] = 0.0f;
        }
        float s2 = 0.0f;
        unsigned bh[4], bl[4];
        #pragma unroll
        for (int k = 0; k < 4; ++k) {
            s2 += vv[2*k]*vv[2*k] + vv[2*k+1]*vv[2*k+1];
            split_pair(vv[2*k], vv[2*k+1], bh[k], bl[k]);
        }
        const unsigned nbw = split_scalar(s2 * rls2p);
        u32x4 bw;
        #pragma unroll
        for (int k = 0; k < 4; ++k) {
            unsigned seed = (k == 0) ? 0x3F803F80u : ((k == 1) ? nbw : 0u);
            bw[k] = (g == 3) ? seed : ((g == 2) ? bl[k] : bh[k]);
        }
        bfrag[c] = __builtin_bit_cast(short8v, bw);
    }

    __syncthreads();

    // ---- compute: NIT iterations of 16 rows x 32 cols, packed-f32 tail ----
    const f32x2 LN2v   = {0.6931471805599453f, 0.6931471805599453f};
    const f32x2 LN2S3v = {0.16015660576973906f, 0.16015660576973906f};
    const f32x2 ONEv   = {1.0f, 1.0f};
    const f32x2 EPSv   = {1e-20f, 1e-20f};

    // A-fragment part select: g0/g2 -> hi, g1 -> lo, g3 -> seed
    const int poff  = (g == 1) ? 16 : ((g == 3) ? 32 : 0);
    const char* pa  = lds + r15 * RSTRIDE + poff;
    const char* pal = lds + ROWS_PER_BLOCK * RSTRIDE + g * 16;

    f32x4 zq = {0.0f, 0.0f, 0.0f, 0.0f};
    f32x2 acc = {0.0f, 0.0f};

    #pragma unroll 4
    for (int it = 0; it < NIT; ++it) {
        short8v afrag = *(const short8v*)(pa + it * (16 * RSTRIDE));
        f32x4   cal   = *(const f32x4*)(pal + it * 64);

        f32x4 d0 = __builtin_amdgcn_mfma_f32_16x16x32_bf16(afrag, bfrag[0], zq, 0, 0, 0);
        f32x4 d1 = __builtin_amdgcn_mfma_f32_16x16x32_bf16(afrag, bfrag[1], zq, 0, 0, 0);

        #pragma unroll
        for (int q = 0; q < 4; ++q) {
            f32x2 dv = {d0[q], d1[q]};
            f32x2 uv = __builtin_elementwise_max(dv, EPSv);   // v_pk_max_f32
            f32x2 tv, ev;
            tv.x = __builtin_amdgcn_sqrtf(uv.x);
            tv.y = __builtin_amdgcn_sqrtf(uv.y);
            ev.x = __builtin_amdgcn_exp2f(-tv.x);
            ev.y = __builtin_amdgcn_exp2f(-tv.y);
            f32x2 pm = LN2v * tv + (LN2S3v * uv + ONEv);      // 2x v_pk_fma_f32
            f32x2 pe = pm * ev;                               // v_pk_mul_f32
            f32x2 cv = {cal[q], cal[q]};
            acc = pe * cv + acc;                              // v_pk_fma_f32
        }
    }

    float acc0 = acc.x, acc1 = acc.y;

    // reduce over the 4 row-groups; lanes 0-15 of each wave hold column sums
    acc0 += __shfl_xor(acc0, 16);
    acc0 += __shfl_xor(acc0, 32);
    acc1 += __shfl_xor(acc1, 16);
    acc1 += __shfl_xor(acc1, 32);
    if (g == 0) {
        float* dst = part + (size_t)blockIdx.y * M;
        if (j0 < M) dst[j0] = w * acc0;
        if (j1 < M) dst[j1] = w * acc1;
    }
}

__global__ __launch_bounds__(128) void reduce_cols(
    const float* __restrict__ part, float* __restrict__ out,
    int M, int nparts)
{
    const int j = blockIdx.x * 128 + threadIdx.x;
    if (j >= M) return;
    float a = 0.0f;
    #pragma unroll 8
    for (int k = 0; k < nparts; ++k)
        a += part[(size_t)k * M + j];
    out[j] = a;
}

extern "C" void kernel_launch(void* const* d_in, const int* in_sizes, int n_in,
                              void* d_out, int out_size, void* d_ws, size_t ws_size,
                              hipStream_t stream) {
    const float* x     = (const float*)d_in[0];
    const float* xobs  = (const float*)d_in[1];
    const float* alpha = (const float*)d_in[2];
    const float* tfl   = (const float*)d_in[3];
    const float* ls    = (const float*)d_in[4];
    const int*   dro   = (const int*)d_in[5];
    const int*   drx   = (const int*)d_in[6];
    float* out = (float*)d_out;

    const int M  = in_sizes[0] / DPT;
    const int N  = in_sizes[1] / DPT;
    const int ND = in_sizes[5] / 2;
    const int nparts = (N + ROWS_PER_BLOCK - 1) / ROWS_PER_BLOCK;

    float* part = (float*)d_ws;   // nparts * M * 4 B

    dim3 grid((M + COLS_PER_BLOCK - 1) / COLS_PER_BLOCK, nparts);
    matern_main<<<grid, dim3(BLOCK), 0, stream>>>(
        x, xobs, alpha, tfl, ls, dro, drx, part, M, N, ND);

    reduce_cols<<<dim3((M + 127) / 128), dim3(128), 0, stream>>>(
        part, out, M, nparts);
}